// Round 14
// baseline (326.315 us; speedup 1.0000x reference)
//
#include <hip/hip_runtime.h>
#include <hip/hip_bf16.h>
#include <hip/hip_fp16.h>

// R23: R22 + alpha FUSED into reduce's batch preload (in-lane):
//      each lane computes its record's alpha from Sb/Rb/Qb rows (4x uint4
//      vector loads, w in SGPRs via uniform scalar loads, sigmoid in-lane).
//      alpha_kernel + af array deleted (-8MB W, -8MB R, -1 launch, -~45us);
//      reduce gains ~50MB Sb miss traffic. No grid shapes changed.
//   pack_hist -> scan3(hmat) -> scatter1 -> bucket_sort (hdrS + offs) ->
//   proj2(Hw,Rw f16) -> reduce (fused alpha + f16 consume).

typedef __attribute__((ext_vector_type(8))) short bf16x8;
typedef __attribute__((ext_vector_type(4))) float f32x4;
typedef __attribute__((ext_vector_type(2))) float f32x2;

__device__ inline unsigned short f2bf(float x) {
    unsigned u = __float_as_uint(x);
    u += 0x7FFF + ((u >> 16) & 1);          // round-to-nearest-even
    return (unsigned short)(u >> 16);
}
__device__ inline float bf2f(unsigned short b) {
    return __uint_as_float(((unsigned)b) << 16);
}
__device__ inline __half2 u2h2(unsigned u) {
    return __builtin_bit_cast(__half2, u);
}

__device__ inline bf16x8 pack8(float4 a, float4 b) {
    bf16x8 r;
    r[0] = (short)f2bf(a.x); r[1] = (short)f2bf(a.y);
    r[2] = (short)f2bf(a.z); r[3] = (short)f2bf(a.w);
    r[4] = (short)f2bf(b.x); r[5] = (short)f2bf(b.y);
    r[6] = (short)f2bf(b.z); r[7] = (short)f2bf(b.w);
    return r;
}

// Dual-source projection: out[m][n] = f16/bf16( sum_d X[m][d]*W[n][d] ),
// d<64, n<NT*16. Blocks [0,nb1) -> X1/out1, rest -> X2/out2. MFMA, no LDS.
template<int NT, bool F16>
__global__ void proj_mfma2_kernel(const float* __restrict__ X1, int n1,
                                  const float* __restrict__ X2, int n2,
                                  const float* __restrict__ W,
                                  unsigned short* __restrict__ out1,
                                  unsigned short* __restrict__ out2) {
    int nb1 = (n1 + 63) / 64;
    const float* X; unsigned short* out; int nrows, mblk;
    if ((int)blockIdx.x < nb1) { X = X1; out = out1; nrows = n1; mblk = blockIdx.x; }
    else                        { X = X2; out = out2; nrows = n2; mblk = blockIdx.x - nb1; }

    int lane = threadIdx.x & 63;
    int wv   = threadIdx.x >> 6;
    int m0   = (mblk * 4 + wv) * 16;
    if (m0 >= nrows) return;
    int lr = lane & 15;        // row-in-tile for A/B, col for C
    int lk = lane >> 4;        // k-block 0..3 for A/B, row-block for C

    bf16x8 bfr[NT][2];
#pragma unroll
    for (int nt = 0; nt < NT; ++nt)
#pragma unroll
        for (int ks = 0; ks < 2; ++ks) {
            const float* wp = W + (size_t)(nt * 16 + lr) * 64 + ks * 32 + lk * 8;
            float4 w0 = *(const float4*)wp;
            float4 w1 = *(const float4*)(wp + 4);
            bfr[nt][ks] = pack8(w0, w1);
        }

    int row = m0 + lr;
    if (row >= nrows) row = nrows - 1;
    const float* xp = X + (size_t)row * 64 + lk * 8;
    float4 x0 = *(const float4*)xp;
    float4 x1 = *(const float4*)(xp + 4);
    float4 x2 = *(const float4*)(xp + 32);
    float4 x3 = *(const float4*)(xp + 36);
    bf16x8 a0 = pack8(x0, x1);
    bf16x8 a1 = pack8(x2, x3);

    f32x4 acc[NT];
#pragma unroll
    for (int nt = 0; nt < NT; ++nt) {
        acc[nt] = (f32x4){0.f, 0.f, 0.f, 0.f};
        acc[nt] = __builtin_amdgcn_mfma_f32_16x16x32_bf16(a0, bfr[nt][0], acc[nt], 0, 0, 0);
        acc[nt] = __builtin_amdgcn_mfma_f32_16x16x32_bf16(a1, bfr[nt][1], acc[nt], 0, 0, 0);
    }

#pragma unroll
    for (int nt = 0; nt < NT; ++nt)
#pragma unroll
        for (int r = 0; r < 4; ++r) {
            int ro = m0 + lk * 4 + r;
            if (ro < nrows) {
                unsigned short bits;
                if (F16) {
                    __half h = __float2half(acc[nt][r]);
                    bits = __builtin_bit_cast(unsigned short, h);
                } else {
                    bits = f2bf(acc[nt][r]);
                }
                out[(size_t)ro * (NT * 16) + nt * 16 + lr] = bits;
            }
        }
}

__global__ void qproj_bf16_kernel(const int* __restrict__ q_rel, const float* __restrict__ rela,
                                  const float* __restrict__ Wqr, const float* __restrict__ bqr,
                                  unsigned* __restrict__ Qb, int batch) {
    int tid = threadIdx.x;
    int b = tid >> 5, k = tid & 31;
    if (b >= batch) return;
    int qr = q_rel[b];
    const float* x = rela + (size_t)qr * 64;
    const float* w = Wqr + (size_t)k * 64;
    float acc = bqr[k];
    for (int d = 0; d < 64; ++d) acc += w[d] * x[d];
    float other = __shfl_xor(acc, 1, 64);
    if ((k & 1) == 0) {
        unsigned lo = f2bf(acc), hi = f2bf(other);
        Qb[b * 16 + (k >> 1)] = lo | (hi << 16);
    }
}

// ---- sort stage 1: pack records + coarse histogram (obj>>9) ----
// 256 threads * 32 edges = 8192 edges/block.
// pk2[e] = { sub | rel<<17 | ridx<<26 , obj }
__global__ void pack_hist_kernel(const int4* __restrict__ edges4, int2* __restrict__ pk2,
                                 int* __restrict__ hmat, int n_edge, int NB) {
    __shared__ int hist[256];
    int tid = threadIdx.x, blk = blockIdx.x;
    hist[tid] = 0;
    __syncthreads();
    int unit0 = blk * 2048;   // 4-edge units per block: 8192/4 = 2048
#pragma unroll
    for (int k = 0; k < 8; ++k) {
        int u = unit0 + k * 256 + tid;
        int base = u * 4;
        if (base >= n_edge) break;
        if (base + 4 <= n_edge) {
            const int4* p = edges4 + (size_t)u * 6;
            int4 v0 = p[0], v1 = p[1], v2 = p[2], v3 = p[3], v4 = p[4], v5 = p[5];
            atomicAdd(&hist[v1.y >> 9], 1);
            atomicAdd(&hist[v2.w >> 9], 1);
            atomicAdd(&hist[v4.y >> 9], 1);
            atomicAdd(&hist[v5.w >> 9], 1);
            int4 o0, o1;
            o0.x = v1.x | (v0.z << 17) | (v0.x << 26); o0.y = v1.y;
            o0.z = v2.z | (v2.x << 17) | (v1.z << 26); o0.w = v2.w;
            o1.x = v4.x | (v3.z << 17) | (v3.x << 26); o1.y = v4.y;
            o1.z = v5.z | (v5.x << 17) | (v4.z << 26); o1.w = v5.w;
            int4* q = (int4*)pk2 + (size_t)u * 2;
            q[0] = o0;
            q[1] = o1;
        } else {
            const int* ei = (const int*)edges4;
            for (int e = base; e < n_edge; ++e) {
                const int* ep = ei + (size_t)e * 6;
                int ridx = ep[0], rel = ep[2], sub = ep[4], obj = ep[5];
                atomicAdd(&hist[obj >> 9], 1);
                pk2[e] = make_int2(sub | (rel << 17) | (ridx << 26), obj);
            }
        }
    }
    __syncthreads();
    hmat[tid * NB + blk] = hist[tid];   // bin-major for the scan
}

// ---- multi-block exclusive scan (in[0..N) -> out[0..N], out[N]=total) ----
#define SCAN_CHUNK 1024

__global__ void scan_partial_kernel(const int* __restrict__ counts, int* __restrict__ bsum,
                                    int N) {
    __shared__ int s[256];
    int base = blockIdx.x * SCAN_CHUNK;
    int tid = threadIdx.x;
    int sum = 0;
#pragma unroll
    for (int k = 0; k < 4; ++k) {
        int idx = base + k * 256 + tid;
        if (idx < N) sum += counts[idx];
    }
    s[tid] = sum;
    __syncthreads();
    for (int off = 128; off > 0; off >>= 1) {
        if (tid < off) s[tid] += s[tid + off];
        __syncthreads();
    }
    if (tid == 0) bsum[blockIdx.x] = s[0];
}

__global__ void scan_bsum_kernel(int* __restrict__ bsum, int* __restrict__ offs, int B, int N) {
    __shared__ int s[1024];
    int tid = threadIdx.x;
    int v = (tid < B) ? bsum[tid] : 0;
    s[tid] = v;
    __syncthreads();
    for (int off = 1; off < 1024; off <<= 1) {
        int t = (tid >= off) ? s[tid - off] : 0;
        __syncthreads();
        s[tid] += t;
        __syncthreads();
    }
    if (tid < B) bsum[tid] = s[tid] - v;   // exclusive block prefix
    if (tid == 0) offs[N] = s[1023];       // grand total
}

__global__ void scan_final_kernel(const int* __restrict__ counts, const int* __restrict__ bsum,
                                  int* __restrict__ offs, int N) {
    __shared__ int s[256];
    int base = blockIdx.x * SCAN_CHUNK;
    int tid = threadIdx.x;
    int v[4];
    int sum = 0;
#pragma unroll
    for (int k = 0; k < 4; ++k) {
        int idx = base + tid * 4 + k;
        v[k] = (idx < N) ? counts[idx] : 0;
        sum += v[k];
    }
    s[tid] = sum;
    __syncthreads();
    for (int off = 1; off < 256; off <<= 1) {
        int t = (tid >= off) ? s[tid - off] : 0;
        __syncthreads();
        s[tid] += t;
        __syncthreads();
    }
    int run = bsum[blockIdx.x] + s[tid] - sum;
#pragma unroll
    for (int k = 0; k < 4; ++k) {
        int idx = base + tid * 4 + k;
        if (idx < N) offs[idx] = run;
        run += v[k];
    }
}

// ---- sort stage 2: scatter into coarse buckets (LDS cursors only) ----
__global__ void scatter1_kernel(const int2* __restrict__ pk2, const int* __restrict__ hscan,
                                int2* __restrict__ outrec, int n_edge, int NB) {
    __shared__ int cur[256];
    int tid = threadIdx.x, blk = blockIdx.x;
    cur[tid] = hscan[tid * NB + blk];
    __syncthreads();
    int unit0 = blk * 2048;
#pragma unroll
    for (int k = 0; k < 8; ++k) {
        int u = unit0 + k * 256 + tid;
        int base = u * 4;
        if (base >= n_edge) break;
        if (base + 4 <= n_edge) {
            const int4* q = (const int4*)pk2 + (size_t)u * 2;
            int4 a = q[0], b = q[1];
            int p0 = atomicAdd(&cur[(a.y >> 9) & 0xFF], 1);
            int p1 = atomicAdd(&cur[(a.w >> 9) & 0xFF], 1);
            int p2 = atomicAdd(&cur[(b.y >> 9) & 0xFF], 1);
            int p3 = atomicAdd(&cur[(b.w >> 9) & 0xFF], 1);
            outrec[p0] = make_int2(a.x, a.y);
            outrec[p1] = make_int2(a.z, a.w);
            outrec[p2] = make_int2(b.x, b.y);
            outrec[p3] = make_int2(b.z, b.w);
        } else {
            for (int e = base; e < n_edge; ++e) {
                int2 r = pk2[e];
                int p = atomicAdd(&cur[(r.y >> 9) & 0xFF], 1);
                outrec[p] = r;
            }
        }
    }
}

// ---- sort stage 3: per-bucket LDS counting sort by obj&511 ----
// Emits SORTED 4B HEADERS into hdrS and offs[obj] = bucket_start + within-
// bucket exclusive base (covers obj == n_node too).
#define BS_CAP 12288
__global__ __launch_bounds__(512) void bucket_sort_kernel(const int2* __restrict__ in,
                                                          const int* __restrict__ hscan,
                                                          int* __restrict__ hdrS,
                                                          int* __restrict__ offs,
                                                          int NB, int n_node) {
    __shared__ int hist[512];
    __shared__ int sbase[512];
    __shared__ int cur[512];
    __shared__ int2 st[BS_CAP];          // ~96 KB stage (gfx950: 160 KiB LDS/CU)
    int b = blockIdx.x, tid = threadIdx.x;
    int start = hscan[b * NB];
    int end   = hscan[(b + 1) * NB];
    int size  = end - start;
    hist[tid] = 0;
    __syncthreads();
    bool inlds = (size <= BS_CAP);
    if (inlds) {
        for (int i = tid; i < size; i += 512) {
            int2 v = in[start + i];
            st[i] = v;
            atomicAdd(&hist[v.y & 511], 1);
        }
    } else {
        for (int i = tid; i < size; i += 512) {
            int2 v = in[start + i];
            atomicAdd(&hist[v.y & 511], 1);
        }
    }
    __syncthreads();
    int h = hist[tid];
    sbase[tid] = h;
    __syncthreads();
    for (int off = 1; off < 512; off <<= 1) {
        int t = (tid >= off) ? sbase[tid - off] : 0;
        __syncthreads();
        sbase[tid] += t;
        __syncthreads();
    }
    int ebase = sbase[tid] - h;          // exclusive base within bucket
    cur[tid] = ebase;
    int obj = (b << 9) | tid;
    if (obj <= n_node) offs[obj] = start + ebase;
    __syncthreads();
    if (inlds) {
        for (int i = tid; i < size; i += 512) {
            int2 r = st[i];
            int p = atomicAdd(&cur[r.y & 511], 1);
            hdrS[start + p] = r.x;
        }
    } else {
        for (int i = tid; i < size; i += 512) {
            int2 r = in[start + i];
            int p = atomicAdd(&cur[r.y & 511], 1);
            hdrS[start + p] = r.x;
        }
    }
}

// per-uint attn unit: 2 dims, relu(S+R+Q) dot w
__device__ inline float eunit(unsigned sv, unsigned rv, unsigned qv, float w0, float w1) {
    float a0 = fmaxf(bf2f((unsigned short)sv) + bf2f((unsigned short)rv)
                     + bf2f((unsigned short)qv), 0.f);
    float a1 = fmaxf(bf2f((unsigned short)(sv >> 16)) + bf2f((unsigned short)(rv >> 16))
                     + bf2f((unsigned short)(qv >> 16)), 0.f);
    return a0 * w0 + a1 * w1;
}

// reduce with FUSED alpha: one 64-lane wave per node. Batch preload: each lane
// loads its record's header AND computes alpha in-lane (Sb row via 4x uint4,
// Rb/Qb L1-resident, w in SGPRs). Then the R19 depth-4 pipelined f16 gather
// consume, with `a` broadcast via the existing bpermute path.
__global__ void reduce_kernel(const int* __restrict__ hdrS,
                              const int* __restrict__ offs,
                              const uint4* __restrict__ Sb4,
                              const uint4* __restrict__ Rb4,
                              const uint4* __restrict__ Qb4,
                              const float* __restrict__ wv,   // 32 floats (SGPR)
                              const float* __restrict__ w_alpha_b,
                              const uint2* __restrict__ Hw2,
                              const uint2* __restrict__ Rw2,
                              float4* __restrict__ out4, int n_node) {
    int lane = threadIdx.x & 63;
    int node = blockIdx.x * 4 + (threadIdx.x >> 6);
    if (node >= n_node) return;
    int g = lane >> 4;        // record subgroup 0..3
    int t = lane & 15;        // dim-quad index 0..15
    int start = offs[node], end = offs[node + 1];
    float wb = w_alpha_b[0];
    __half2 acc0 = __float2half2_rn(0.f);
    __half2 acc1 = __float2half2_rn(0.f);

    for (int i = start; i < end; i += 64) {
        int m = end - i;
        if (m > 64) m = 64;
        float a = 0.f;        // a=0 for idle lanes -> tail records contribute 0
        int pk = 0;
        if (lane < m) {
            pk = __builtin_nontemporal_load(&hdrS[i + lane]);
            int sub_ = pk & 0x1FFFF;
            int rel_ = (pk >> 17) & 0x1FF;
            int rix_ = (pk >> 26) & 7;
            const uint4* sp = Sb4 + (size_t)sub_ * 4;
            const uint4* rp = Rb4 + (size_t)rel_ * 4;
            const uint4* qp = Qb4 + (size_t)rix_ * 4;
            float p = 0.f;
#pragma unroll
            for (int u = 0; u < 4; ++u) {
                uint4 s = sp[u], r = rp[u], q = qp[u];
                p += eunit(s.x, r.x, q.x, wv[8 * u + 0], wv[8 * u + 1]);
                p += eunit(s.y, r.y, q.y, wv[8 * u + 2], wv[8 * u + 3]);
                p += eunit(s.z, r.z, q.z, wv[8 * u + 4], wv[8 * u + 5]);
                p += eunit(s.w, r.w, q.w, wv[8 * u + 6], wv[8 * u + 7]);
            }
            a = 1.f / (1.f + __expf(-(p + wb)));
        }
        int nj = (m + 3) >> 2;

        __half2 A0, A1, A2, A3;
        uint2 H0, H1, H2, H3, R0, R1, R2, R3;

#define RD_ISSUE(S, J) do {                                                   \
        int src_ = 4 * (J) + g;                                               \
        bool ok_ = (src_ < m);                                                \
        int s_ = ok_ ? src_ : 0;                                              \
        float a_ = __shfl(a, s_, 64);                                         \
        int p_ = __shfl(pk, s_, 64);                                          \
        A##S = __float2half2_rn(ok_ ? a_ : 0.f);                              \
        int sub_ = p_ & 0x1FFFF, rel_ = (p_ >> 17) & 0x1FF;                   \
        H##S = Hw2[(size_t)sub_ * 16 + t];                                    \
        R##S = Rw2[(size_t)rel_ * 16 + t];                                    \
    } while (0)

#define RD_CONSUME(S) do {                                                    \
        acc0 = __hfma2(A##S, __hadd2(u2h2(H##S.x), u2h2(R##S.x)), acc0);      \
        acc1 = __hfma2(A##S, __hadd2(u2h2(H##S.y), u2h2(R##S.y)), acc1);      \
    } while (0)

        RD_ISSUE(0, 0);
        RD_ISSUE(1, 1);
        RD_ISSUE(2, 2);
        RD_ISSUE(3, 3);
        for (int j = 0; j < nj; j += 4) {
            RD_CONSUME(0); RD_ISSUE(0, j + 4);
            RD_CONSUME(1); RD_ISSUE(1, j + 5);
            RD_CONSUME(2); RD_ISSUE(2, j + 6);
            RD_CONSUME(3); RD_ISSUE(3, j + 7);
        }
#undef RD_ISSUE
#undef RD_CONSUME
    }
    float2 f0 = __half22float2(acc0);
    float2 f1 = __half22float2(acc1);
    f32x4 acc = (f32x4){f0.x, f0.y, f1.x, f1.y};
#pragma unroll
    for (int off = 16; off <= 32; off <<= 1) {
        acc.x += __shfl_xor(acc.x, off, 64);
        acc.y += __shfl_xor(acc.y, off, 64);
        acc.z += __shfl_xor(acc.z, off, 64);
        acc.w += __shfl_xor(acc.w, off, 64);
    }
    if (g == 0)
        __builtin_nontemporal_store(acc, (f32x4*)&out4[(size_t)node * 16 + t]);
}

extern "C" void kernel_launch(void* const* d_in, const int* in_sizes, int n_in,
                              void* d_out, int out_size, void* d_ws, size_t ws_size,
                              hipStream_t stream) {
    const int*   q_rel     = (const int*)d_in[1];
    const float* hidden    = (const float*)d_in[2];
    const int*   edges     = (const int*)d_in[3];
    const float* rela      = (const float*)d_in[7];
    const float* Ws        = (const float*)d_in[8];
    const float* Wr        = (const float*)d_in[9];
    const float* Wqr       = (const float*)d_in[10];
    const float* bqr       = (const float*)d_in[11];
    const float* w_alpha_w = (const float*)d_in[12];
    const float* w_alpha_b = (const float*)d_in[13];
    const float* Wh        = (const float*)d_in[14];

    int n_node = in_sizes[2] / 64;
    int n_edge = in_sizes[3] / 6;
    int n_rel  = in_sizes[7] / 64;
    int batch  = in_sizes[1];

    int NB = (n_edge + 8191) / 8192;        // pack/scatter blocks (8192 edges each)
    int N2 = NB * 256;                      // hmat length
    int n_sblk2 = (N2 + SCAN_CHUNK - 1) / SCAN_CHUNK;

    // workspace layout (~41 MB):
    //   regionP (16 MB): pack_hist out; after scatter1 reused as hdrS (8 MB)
    //   regionQ (16 MB): scatter1 out; after bucket_sort reused as Hw/Rw
    unsigned* Sb   = (unsigned*)d_ws;                     // n_node*16 uints (6.4 MB)
    unsigned* Rb   = Sb + (size_t)n_node * 16;            // n_rel*16
    unsigned* Qb   = Rb + (size_t)n_rel * 16;             // batch*16
    int*   offs    = (int*)(Qb + (size_t)batch * 16);     // n_node+1
    int*   bsum    = offs + n_node + 1;                   // 1024
    int*   hmat    = bsum + 1024;                         // N2
    int*   hscan   = hmat + N2;                           // N2+1
    size_t rec_off = (size_t)(hscan + N2 + 1 - (int*)d_ws);
    rec_off = (rec_off + 3) & ~(size_t)3;                 // align 16B
    int2*  regP    = (int2*)((int*)d_ws + rec_off);       // n_edge int2 (16 MB)
    int2*  regQ    = regP + n_edge;                       // n_edge int2 (16 MB)
    int*   hdrS    = (int*)regP;                          // sorted headers (8 MB)
    unsigned short* Hw = (unsigned short*)regQ;           // n_node*64 f16 (12.8 MB)
    unsigned short* Rw = Hw + (size_t)n_node * 64;        // n_rel*64 - fits in regQ

    {
        int nb = (n_node + 63) / 64 + (n_rel + 63) / 64;
        proj_mfma2_kernel<2, false><<<nb, 256, 0, stream>>>(
            hidden, n_node, rela, n_rel, Ws, (unsigned short*)Sb, (unsigned short*)Rb);
    }
    qproj_bf16_kernel<<<1, 256, 0, stream>>>(q_rel, rela, Wqr, bqr, Qb, batch);

    // --- counting sort by obj (no global atomics) ---
    pack_hist_kernel<<<NB, 256, 0, stream>>>((const int4*)edges, regP, hmat, n_edge, NB);

    scan_partial_kernel<<<n_sblk2, 256, 0, stream>>>(hmat, bsum, N2);
    scan_bsum_kernel<<<1, 1024, 0, stream>>>(bsum, hscan, n_sblk2, N2);
    scan_final_kernel<<<n_sblk2, 256, 0, stream>>>(hmat, bsum, hscan, N2);

    scatter1_kernel<<<NB, 256, 0, stream>>>(regP, hscan, regQ, n_edge, NB);
    bucket_sort_kernel<<<256, 512, 0, stream>>>(regQ, hscan, hdrS, offs, NB, n_node);

    // build Wh-projected f16 gather tables AFTER bucket_sort (overlay regQ)
    {
        int nb = (n_node + 63) / 64 + (n_rel + 63) / 64;
        proj_mfma2_kernel<4, true><<<nb, 256, 0, stream>>>(
            hidden, n_node, rela, n_rel, Wh, Hw, Rw);
    }

    reduce_kernel<<<(n_node + 3) / 4, 256, 0, stream>>>(
        hdrS, offs, (const uint4*)Sb, (const uint4*)Rb, (const uint4*)Qb,
        w_alpha_w, w_alpha_b, (const uint2*)Hw, (const uint2*)Rw,
        (float4*)d_out, n_node);
}

// Round 16
// 304.066 us; speedup vs baseline: 1.0732x; 1.0732x over previous
//
#include <hip/hip_runtime.h>
#include <hip/hip_bf16.h>
#include <hip/hip_fp16.h>

// R24 (resubmit; prior round was a GPU-acquisition timeout, never ran):
//      R22 (best, 306us) + coarse radix 256->512 buckets (obj>>8 / obj&255).
//      bucket_sort was 1 block/CU @ 96KB LDS (grid-starved, R21's signature);
//      now 512 blocks @ 67KB LDS -> 2 blocks/CU resident, 4x wave parallelism.
//      R23's alpha-in-reduce reverted (FETCH +118MB, occupancy 72->50: dead).
//   pack_hist -> scan3(hmat) -> scatter1 -> bucket_sort (hdrS + offs) ->
//   alpha (af) -> proj2(Hw,Rw f16) -> reduce (R19/R22 form).

typedef __attribute__((ext_vector_type(8))) short bf16x8;
typedef __attribute__((ext_vector_type(4))) float f32x4;
typedef __attribute__((ext_vector_type(2))) float f32x2;

__device__ inline unsigned short f2bf(float x) {
    unsigned u = __float_as_uint(x);
    u += 0x7FFF + ((u >> 16) & 1);          // round-to-nearest-even
    return (unsigned short)(u >> 16);
}
__device__ inline float bf2f(unsigned short b) {
    return __uint_as_float(((unsigned)b) << 16);
}
__device__ inline __half2 u2h2(unsigned u) {
    return __builtin_bit_cast(__half2, u);
}

__device__ inline bf16x8 pack8(float4 a, float4 b) {
    bf16x8 r;
    r[0] = (short)f2bf(a.x); r[1] = (short)f2bf(a.y);
    r[2] = (short)f2bf(a.z); r[3] = (short)f2bf(a.w);
    r[4] = (short)f2bf(b.x); r[5] = (short)f2bf(b.y);
    r[6] = (short)f2bf(b.z); r[7] = (short)f2bf(b.w);
    return r;
}

// Dual-source projection: out[m][n] = f16/bf16( sum_d X[m][d]*W[n][d] ),
// d<64, n<NT*16. Blocks [0,nb1) -> X1/out1, rest -> X2/out2. MFMA, no LDS.
template<int NT, bool F16>
__global__ void proj_mfma2_kernel(const float* __restrict__ X1, int n1,
                                  const float* __restrict__ X2, int n2,
                                  const float* __restrict__ W,
                                  unsigned short* __restrict__ out1,
                                  unsigned short* __restrict__ out2) {
    int nb1 = (n1 + 63) / 64;
    const float* X; unsigned short* out; int nrows, mblk;
    if ((int)blockIdx.x < nb1) { X = X1; out = out1; nrows = n1; mblk = blockIdx.x; }
    else                        { X = X2; out = out2; nrows = n2; mblk = blockIdx.x - nb1; }

    int lane = threadIdx.x & 63;
    int wv   = threadIdx.x >> 6;
    int m0   = (mblk * 4 + wv) * 16;
    if (m0 >= nrows) return;
    int lr = lane & 15;        // row-in-tile for A/B, col for C
    int lk = lane >> 4;        // k-block 0..3 for A/B, row-block for C

    bf16x8 bfr[NT][2];
#pragma unroll
    for (int nt = 0; nt < NT; ++nt)
#pragma unroll
        for (int ks = 0; ks < 2; ++ks) {
            const float* wp = W + (size_t)(nt * 16 + lr) * 64 + ks * 32 + lk * 8;
            float4 w0 = *(const float4*)wp;
            float4 w1 = *(const float4*)(wp + 4);
            bfr[nt][ks] = pack8(w0, w1);
        }

    int row = m0 + lr;
    if (row >= nrows) row = nrows - 1;
    const float* xp = X + (size_t)row * 64 + lk * 8;
    float4 x0 = *(const float4*)xp;
    float4 x1 = *(const float4*)(xp + 4);
    float4 x2 = *(const float4*)(xp + 32);
    float4 x3 = *(const float4*)(xp + 36);
    bf16x8 a0 = pack8(x0, x1);
    bf16x8 a1 = pack8(x2, x3);

    f32x4 acc[NT];
#pragma unroll
    for (int nt = 0; nt < NT; ++nt) {
        acc[nt] = (f32x4){0.f, 0.f, 0.f, 0.f};
        acc[nt] = __builtin_amdgcn_mfma_f32_16x16x32_bf16(a0, bfr[nt][0], acc[nt], 0, 0, 0);
        acc[nt] = __builtin_amdgcn_mfma_f32_16x16x32_bf16(a1, bfr[nt][1], acc[nt], 0, 0, 0);
    }

#pragma unroll
    for (int nt = 0; nt < NT; ++nt)
#pragma unroll
        for (int r = 0; r < 4; ++r) {
            int ro = m0 + lk * 4 + r;
            if (ro < nrows) {
                unsigned short bits;
                if (F16) {
                    __half h = __float2half(acc[nt][r]);
                    bits = __builtin_bit_cast(unsigned short, h);
                } else {
                    bits = f2bf(acc[nt][r]);
                }
                out[(size_t)ro * (NT * 16) + nt * 16 + lr] = bits;
            }
        }
}

__global__ void qproj_bf16_kernel(const int* __restrict__ q_rel, const float* __restrict__ rela,
                                  const float* __restrict__ Wqr, const float* __restrict__ bqr,
                                  unsigned* __restrict__ Qb, int batch) {
    int tid = threadIdx.x;
    int b = tid >> 5, k = tid & 31;
    if (b >= batch) return;
    int qr = q_rel[b];
    const float* x = rela + (size_t)qr * 64;
    const float* w = Wqr + (size_t)k * 64;
    float acc = bqr[k];
    for (int d = 0; d < 64; ++d) acc += w[d] * x[d];
    float other = __shfl_xor(acc, 1, 64);
    if ((k & 1) == 0) {
        unsigned lo = f2bf(acc), hi = f2bf(other);
        Qb[b * 16 + (k >> 1)] = lo | (hi << 16);
    }
}

// ---- sort stage 1: pack records + coarse histogram (obj>>8, 512 bins) ----
// 256 threads * 32 edges = 8192 edges/block.
// pk2[e] = { sub | rel<<17 | ridx<<26 , obj }
__global__ void pack_hist_kernel(const int4* __restrict__ edges4, int2* __restrict__ pk2,
                                 int* __restrict__ hmat, int n_edge, int NB) {
    __shared__ int hist[512];
    int tid = threadIdx.x, blk = blockIdx.x;
    hist[tid] = 0;
    hist[tid + 256] = 0;
    __syncthreads();
    int unit0 = blk * 2048;   // 4-edge units per block: 8192/4 = 2048
#pragma unroll
    for (int k = 0; k < 8; ++k) {
        int u = unit0 + k * 256 + tid;
        int base = u * 4;
        if (base >= n_edge) break;
        if (base + 4 <= n_edge) {
            const int4* p = edges4 + (size_t)u * 6;
            int4 v0 = p[0], v1 = p[1], v2 = p[2], v3 = p[3], v4 = p[4], v5 = p[5];
            // edge0: r=v0.x rel=v0.z sub=v1.x obj=v1.y
            // edge1: r=v1.z rel=v2.x sub=v2.z obj=v2.w
            // edge2: r=v3.x rel=v3.z sub=v4.x obj=v4.y
            // edge3: r=v4.z rel=v5.x sub=v5.z obj=v5.w
            atomicAdd(&hist[v1.y >> 8], 1);
            atomicAdd(&hist[v2.w >> 8], 1);
            atomicAdd(&hist[v4.y >> 8], 1);
            atomicAdd(&hist[v5.w >> 8], 1);
            int4 o0, o1;
            o0.x = v1.x | (v0.z << 17) | (v0.x << 26); o0.y = v1.y;
            o0.z = v2.z | (v2.x << 17) | (v1.z << 26); o0.w = v2.w;
            o1.x = v4.x | (v3.z << 17) | (v3.x << 26); o1.y = v4.y;
            o1.z = v5.z | (v5.x << 17) | (v4.z << 26); o1.w = v5.w;
            int4* q = (int4*)pk2 + (size_t)u * 2;
            q[0] = o0;
            q[1] = o1;
        } else {
            const int* ei = (const int*)edges4;
            for (int e = base; e < n_edge; ++e) {
                const int* ep = ei + (size_t)e * 6;
                int ridx = ep[0], rel = ep[2], sub = ep[4], obj = ep[5];
                atomicAdd(&hist[obj >> 8], 1);
                pk2[e] = make_int2(sub | (rel << 17) | (ridx << 26), obj);
            }
        }
    }
    __syncthreads();
    hmat[tid * NB + blk] = hist[tid];               // bin-major for the scan
    hmat[(tid + 256) * NB + blk] = hist[tid + 256];
}

// ---- multi-block exclusive scan (in[0..N) -> out[0..N], out[N]=total) ----
#define SCAN_CHUNK 1024

__global__ void scan_partial_kernel(const int* __restrict__ counts, int* __restrict__ bsum,
                                    int N) {
    __shared__ int s[256];
    int base = blockIdx.x * SCAN_CHUNK;
    int tid = threadIdx.x;
    int sum = 0;
#pragma unroll
    for (int k = 0; k < 4; ++k) {
        int idx = base + k * 256 + tid;
        if (idx < N) sum += counts[idx];
    }
    s[tid] = sum;
    __syncthreads();
    for (int off = 128; off > 0; off >>= 1) {
        if (tid < off) s[tid] += s[tid + off];
        __syncthreads();
    }
    if (tid == 0) bsum[blockIdx.x] = s[0];
}

__global__ void scan_bsum_kernel(int* __restrict__ bsum, int* __restrict__ offs, int B, int N) {
    __shared__ int s[1024];
    int tid = threadIdx.x;
    int v = (tid < B) ? bsum[tid] : 0;
    s[tid] = v;
    __syncthreads();
    for (int off = 1; off < 1024; off <<= 1) {
        int t = (tid >= off) ? s[tid - off] : 0;
        __syncthreads();
        s[tid] += t;
        __syncthreads();
    }
    if (tid < B) bsum[tid] = s[tid] - v;   // exclusive block prefix
    if (tid == 0) offs[N] = s[1023];       // grand total
}

__global__ void scan_final_kernel(const int* __restrict__ counts, const int* __restrict__ bsum,
                                  int* __restrict__ offs, int N) {
    __shared__ int s[256];
    int base = blockIdx.x * SCAN_CHUNK;
    int tid = threadIdx.x;
    int v[4];
    int sum = 0;
#pragma unroll
    for (int k = 0; k < 4; ++k) {
        int idx = base + tid * 4 + k;
        v[k] = (idx < N) ? counts[idx] : 0;
        sum += v[k];
    }
    s[tid] = sum;
    __syncthreads();
    for (int off = 1; off < 256; off <<= 1) {
        int t = (tid >= off) ? s[tid - off] : 0;
        __syncthreads();
        s[tid] += t;
        __syncthreads();
    }
    int run = bsum[blockIdx.x] + s[tid] - sum;
#pragma unroll
    for (int k = 0; k < 4; ++k) {
        int idx = base + tid * 4 + k;
        if (idx < N) offs[idx] = run;
        run += v[k];
    }
}

// ---- sort stage 2: scatter into coarse buckets (512 LDS cursors) ----
__global__ void scatter1_kernel(const int2* __restrict__ pk2, const int* __restrict__ hscan,
                                int2* __restrict__ outrec, int n_edge, int NB) {
    __shared__ int cur[512];
    int tid = threadIdx.x, blk = blockIdx.x;
    cur[tid] = hscan[tid * NB + blk];
    cur[tid + 256] = hscan[(tid + 256) * NB + blk];
    __syncthreads();
    int unit0 = blk * 2048;
#pragma unroll
    for (int k = 0; k < 8; ++k) {
        int u = unit0 + k * 256 + tid;
        int base = u * 4;
        if (base >= n_edge) break;
        if (base + 4 <= n_edge) {
            const int4* q = (const int4*)pk2 + (size_t)u * 2;
            int4 a = q[0], b = q[1];
            int p0 = atomicAdd(&cur[(a.y >> 8) & 0x1FF], 1);
            int p1 = atomicAdd(&cur[(a.w >> 8) & 0x1FF], 1);
            int p2 = atomicAdd(&cur[(b.y >> 8) & 0x1FF], 1);
            int p3 = atomicAdd(&cur[(b.w >> 8) & 0x1FF], 1);
            outrec[p0] = make_int2(a.x, a.y);
            outrec[p1] = make_int2(a.z, a.w);
            outrec[p2] = make_int2(b.x, b.y);
            outrec[p3] = make_int2(b.z, b.w);
        } else {
            for (int e = base; e < n_edge; ++e) {
                int2 r = pk2[e];
                int p = atomicAdd(&cur[(r.y >> 8) & 0x1FF], 1);
                outrec[p] = r;
            }
        }
    }
}

// ---- sort stage 3: per-bucket LDS counting sort by obj&255 ----
// 512 blocks (one per coarse bucket), 67KB LDS -> 2 blocks/CU resident.
// Emits SORTED 4B HEADERS into hdrS and offs[obj] = bucket_start + within-
// bucket exclusive base (covers obj == n_node too).
#define BS_CAP 8192
__global__ __launch_bounds__(512) void bucket_sort_kernel(const int2* __restrict__ in,
                                                          const int* __restrict__ hscan,
                                                          int* __restrict__ hdrS,
                                                          int* __restrict__ offs,
                                                          int NB, int n_node) {
    __shared__ int hist[256];
    __shared__ int sbase[256];
    __shared__ int cur[256];
    __shared__ int2 st[BS_CAP];          // 64 KB stage
    int b = blockIdx.x, tid = threadIdx.x;
    int start = hscan[b * NB];
    int end   = hscan[(b + 1) * NB];
    int size  = end - start;
    if (tid < 256) hist[tid] = 0;
    __syncthreads();
    bool inlds = (size <= BS_CAP);
    if (inlds) {
        for (int i = tid; i < size; i += 512) {
            int2 v = in[start + i];
            st[i] = v;
            atomicAdd(&hist[v.y & 255], 1);
        }
    } else {
        for (int i = tid; i < size; i += 512) {
            int2 v = in[start + i];
            atomicAdd(&hist[v.y & 255], 1);
        }
    }
    __syncthreads();
    int h = 0;
    if (tid < 256) { h = hist[tid]; sbase[tid] = h; }
    __syncthreads();
    for (int off = 1; off < 256; off <<= 1) {
        int t = (tid >= off && tid < 256) ? sbase[tid - off] : 0;
        __syncthreads();
        if (tid < 256) sbase[tid] += t;
        __syncthreads();
    }
    if (tid < 256) {
        int ebase = sbase[tid] - h;      // exclusive base within bucket
        cur[tid] = ebase;
        int obj = (b << 8) | tid;
        if (obj <= n_node) offs[obj] = start + ebase;
    }
    __syncthreads();
    if (inlds) {
        for (int i = tid; i < size; i += 512) {
            int2 r = st[i];
            int p = atomicAdd(&cur[r.y & 255], 1);
            hdrS[start + p] = r.x;
        }
    } else {
        for (int i = tid; i < size; i += 512) {
            int2 r = in[start + i];
            int p = atomicAdd(&cur[r.y & 255], 1);
            hdrS[start + p] = r.x;
        }
    }
}

__device__ inline float edot(unsigned sv, unsigned rv, unsigned qv, float2 w) {
    float a0 = fmaxf(bf2f((unsigned short)sv) + bf2f((unsigned short)rv)
                     + bf2f((unsigned short)qv), 0.f);
    float a1 = fmaxf(bf2f((unsigned short)(sv >> 16)) + bf2f((unsigned short)(rv >> 16))
                     + bf2f((unsigned short)(qv >> 16)), 0.f);
    return a0 * w.x + a1 * w.y;
}

// 16 lanes per group, 4 SORTED headers per group (one int4 broadcast load);
// writes the 4B alpha array contiguously.
__global__ void alpha_kernel(const int* __restrict__ hdrS,
                             const unsigned* __restrict__ Sb,
                             const unsigned* __restrict__ Rb,
                             const unsigned* __restrict__ Qb,
                             const float2* __restrict__ w2,
                             const float* __restrict__ w_alpha_b,
                             float* __restrict__ af,
                             int n_edge) {
    int tid = threadIdx.x;
    int lane = tid & 15;
    int e0 = (blockIdx.x * 16 + (tid >> 4)) * 4;
    if (e0 >= n_edge) return;
    int4 h4 = *(const int4*)(hdrS + e0);   // may overread <=12B into workspace (safe)
    int h0 = h4.x, h1 = h4.y, h2 = h4.z, h3 = h4.w;
    float2 w = w2[lane];
    unsigned sv0 = Sb[(size_t)(h0 & 0x1FFFF) * 16 + lane];
    unsigned sv1 = Sb[(size_t)(h1 & 0x1FFFF) * 16 + lane];
    unsigned sv2 = Sb[(size_t)(h2 & 0x1FFFF) * 16 + lane];
    unsigned sv3 = Sb[(size_t)(h3 & 0x1FFFF) * 16 + lane];
    unsigned rv0 = Rb[(size_t)((h0 >> 17) & 0x1FF) * 16 + lane];
    unsigned rv1 = Rb[(size_t)((h1 >> 17) & 0x1FF) * 16 + lane];
    unsigned rv2 = Rb[(size_t)((h2 >> 17) & 0x1FF) * 16 + lane];
    unsigned rv3 = Rb[(size_t)((h3 >> 17) & 0x1FF) * 16 + lane];
    unsigned qv0 = Qb[((h0 >> 26) & 7) * 16 + lane];
    unsigned qv1 = Qb[((h1 >> 26) & 7) * 16 + lane];
    unsigned qv2 = Qb[((h2 >> 26) & 7) * 16 + lane];
    unsigned qv3 = Qb[((h3 >> 26) & 7) * 16 + lane];
    float p0 = edot(sv0, rv0, qv0, w);
    float p1 = edot(sv1, rv1, qv1, w);
    float p2 = edot(sv2, rv2, qv2, w);
    float p3 = edot(sv3, rv3, qv3, w);
#pragma unroll
    for (int off = 8; off > 0; off >>= 1) {
        p0 += __shfl_xor(p0, off, 16);
        p1 += __shfl_xor(p1, off, 16);
        p2 += __shfl_xor(p2, off, 16);
        p3 += __shfl_xor(p3, off, 16);
    }
    if (lane < 4 && e0 + lane < n_edge) {
        float p = p0;
        if (lane == 1) p = p1;
        if (lane == 2) p = p2;
        if (lane == 3) p = p3;
        float alpha = 1.f / (1.f + __expf(-(p + w_alpha_b[0])));
        af[e0 + lane] = alpha;                // contiguous (sorted order)
    }
}

// reduce (R19 form, split streams): one 64-lane wave per node; coalesced
// {hdr, alpha} batch preload; depth-4 software-pipelined gathers of the f16
// Wh tables (slot broadcast via bpermute); packed-f16 accumulate.
__global__ void reduce_kernel(const int* __restrict__ hdrS, const float* __restrict__ af,
                              const int* __restrict__ offs,
                              const uint2* __restrict__ Hw2,
                              const uint2* __restrict__ Rw2,
                              float4* __restrict__ out4, int n_node) {
    int lane = threadIdx.x & 63;
    int node = blockIdx.x * 4 + (threadIdx.x >> 6);
    if (node >= n_node) return;
    int g = lane >> 4;        // record subgroup 0..3
    int t = lane & 15;        // dim-quad index 0..15
    int start = offs[node], end = offs[node + 1];
    __half2 acc0 = __float2half2_rn(0.f);
    __half2 acc1 = __float2half2_rn(0.f);

    for (int i = start; i < end; i += 64) {
        int m = end - i;
        if (m > 64) m = 64;
        float a = 0.f;        // a=0 for idle lanes -> tail records contribute 0
        int pk = 0;
        if (lane < m) {
            a  = __builtin_nontemporal_load(&af[i + lane]);
            pk = __builtin_nontemporal_load(&hdrS[i + lane]);
        }
        int nj = (m + 3) >> 2;

        __half2 A0, A1, A2, A3;
        uint2 H0, H1, H2, H3, R0, R1, R2, R3;

#define RD_ISSUE(S, J) do {                                                   \
        int src_ = 4 * (J) + g;                                               \
        bool ok_ = (src_ < m);                                                \
        int s_ = ok_ ? src_ : 0;                                              \
        float a_ = __shfl(a, s_, 64);                                         \
        int p_ = __shfl(pk, s_, 64);                                          \
        A##S = __float2half2_rn(ok_ ? a_ : 0.f);                              \
        int sub_ = p_ & 0x1FFFF, rel_ = (p_ >> 17) & 0x1FF;                   \
        H##S = Hw2[(size_t)sub_ * 16 + t];                                    \
        R##S = Rw2[(size_t)rel_ * 16 + t];                                    \
    } while (0)

#define RD_CONSUME(S) do {                                                    \
        acc0 = __hfma2(A##S, __hadd2(u2h2(H##S.x), u2h2(R##S.x)), acc0);      \
        acc1 = __hfma2(A##S, __hadd2(u2h2(H##S.y), u2h2(R##S.y)), acc1);      \
    } while (0)

        RD_ISSUE(0, 0);
        RD_ISSUE(1, 1);
        RD_ISSUE(2, 2);
        RD_ISSUE(3, 3);
        for (int j = 0; j < nj; j += 4) {
            RD_CONSUME(0); RD_ISSUE(0, j + 4);
            RD_CONSUME(1); RD_ISSUE(1, j + 5);
            RD_CONSUME(2); RD_ISSUE(2, j + 6);
            RD_CONSUME(3); RD_ISSUE(3, j + 7);
        }
#undef RD_ISSUE
#undef RD_CONSUME
    }
    float2 f0 = __half22float2(acc0);
    float2 f1 = __half22float2(acc1);
    f32x4 acc = (f32x4){f0.x, f0.y, f1.x, f1.y};
#pragma unroll
    for (int off = 16; off <= 32; off <<= 1) {
        acc.x += __shfl_xor(acc.x, off, 64);
        acc.y += __shfl_xor(acc.y, off, 64);
        acc.z += __shfl_xor(acc.z, off, 64);
        acc.w += __shfl_xor(acc.w, off, 64);
    }
    if (g == 0)
        __builtin_nontemporal_store(acc, (f32x4*)&out4[(size_t)node * 16 + t]);
}

extern "C" void kernel_launch(void* const* d_in, const int* in_sizes, int n_in,
                              void* d_out, int out_size, void* d_ws, size_t ws_size,
                              hipStream_t stream) {
    const int*   q_rel     = (const int*)d_in[1];
    const float* hidden    = (const float*)d_in[2];
    const int*   edges     = (const int*)d_in[3];
    const float* rela      = (const float*)d_in[7];
    const float* Ws        = (const float*)d_in[8];
    const float* Wr        = (const float*)d_in[9];
    const float* Wqr       = (const float*)d_in[10];
    const float* bqr       = (const float*)d_in[11];
    const float* w_alpha_w = (const float*)d_in[12];
    const float* w_alpha_b = (const float*)d_in[13];
    const float* Wh        = (const float*)d_in[14];

    int n_node = in_sizes[2] / 64;
    int n_edge = in_sizes[3] / 6;
    int n_rel  = in_sizes[7] / 64;
    int batch  = in_sizes[1];

    int NB = (n_edge + 8191) / 8192;        // pack/scatter blocks (8192 edges each)
    int N2 = NB * 512;                      // hmat length (512 coarse buckets)
    int n_sblk2 = (N2 + SCAN_CHUNK - 1) / SCAN_CHUNK;

    // workspace layout (~41 MB):
    //   regionP (16 MB): pack_hist out; after scatter1 reused as hdrS (8) + af (8)
    //   regionQ (16 MB): scatter1 out; after bucket_sort reused as Hw/Rw
    unsigned* Sb   = (unsigned*)d_ws;                     // n_node*16 uints (6.4 MB)
    unsigned* Rb   = Sb + (size_t)n_node * 16;            // n_rel*16
    unsigned* Qb   = Rb + (size_t)n_rel * 16;             // batch*16
    int*   offs    = (int*)(Qb + (size_t)batch * 16);     // n_node+1
    int*   bsum    = offs + n_node + 1;                   // 1024
    int*   hmat    = bsum + 1024;                         // N2
    int*   hscan   = hmat + N2;                           // N2+1
    size_t rec_off = (size_t)(hscan + N2 + 1 - (int*)d_ws);
    rec_off = (rec_off + 3) & ~(size_t)3;                 // align 16B
    int2*  regP    = (int2*)((int*)d_ws + rec_off);       // n_edge int2 (16 MB)
    int2*  regQ    = regP + n_edge;                       // n_edge int2 (16 MB)
    int*   hdrS    = (int*)regP;                          // sorted headers (8 MB)
    float* af      = (float*)(hdrS + n_edge);             // alpha array (8 MB)
    unsigned short* Hw = (unsigned short*)regQ;           // n_node*64 f16 (12.8 MB)
    unsigned short* Rw = Hw + (size_t)n_node * 64;        // n_rel*64 - fits in regQ

    {
        int nb = (n_node + 63) / 64 + (n_rel + 63) / 64;
        proj_mfma2_kernel<2, false><<<nb, 256, 0, stream>>>(
            hidden, n_node, rela, n_rel, Ws, (unsigned short*)Sb, (unsigned short*)Rb);
    }
    qproj_bf16_kernel<<<1, 256, 0, stream>>>(q_rel, rela, Wqr, bqr, Qb, batch);

    // --- counting sort by obj (no global atomics) ---
    pack_hist_kernel<<<NB, 256, 0, stream>>>((const int4*)edges, regP, hmat, n_edge, NB);

    scan_partial_kernel<<<n_sblk2, 256, 0, stream>>>(hmat, bsum, N2);
    scan_bsum_kernel<<<1, 1024, 0, stream>>>(bsum, hscan, n_sblk2, N2);
    scan_final_kernel<<<n_sblk2, 256, 0, stream>>>(hmat, bsum, hscan, N2);

    scatter1_kernel<<<NB, 256, 0, stream>>>(regP, hscan, regQ, n_edge, NB);
    bucket_sort_kernel<<<512, 512, 0, stream>>>(regQ, hscan, hdrS, offs, NB, n_node);

    alpha_kernel<<<(n_edge + 63) / 64, 256, 0, stream>>>(
        hdrS, Sb, Rb, Qb, (const float2*)w_alpha_w, w_alpha_b, af, n_edge);

    // build Wh-projected f16 gather tables AFTER bucket_sort (overlay regQ)
    {
        int nb = (n_node + 63) / 64 + (n_rel + 63) / 64;
        proj_mfma2_kernel<4, true><<<nb, 256, 0, stream>>>(
            hidden, n_node, rela, n_rel, Wh, Hw, Rw);
    }

    reduce_kernel<<<(n_node + 3) / 4, 256, 0, stream>>>(
        hdrS, af, offs, (const uint2*)Hw, (const uint2*)Rw, (float4*)d_out, n_node);
}

// Round 17
// 303.228 us; speedup vs baseline: 1.0761x; 1.0028x over previous
//
#include <hip/hip_runtime.h>
#include <hip/hip_bf16.h>
#include <hip/hip_fp16.h>

// R25: R24 (best, 304us) + LDS-staged scatter1: block-local 512-bin counting
//      sort in LDS, then bucket-contiguous BURST writes (consecutive lanes ->
//      consecutive addresses) instead of 64-way scattered 8B stores.
//   pack_hist -> scan3(hmat) -> scatter1(staged) -> bucket_sort (hdrS+offs) ->
//   alpha (af) -> proj2(Hw,Rw f16) -> reduce (R19/R22 form).

typedef __attribute__((ext_vector_type(8))) short bf16x8;
typedef __attribute__((ext_vector_type(4))) float f32x4;
typedef __attribute__((ext_vector_type(2))) float f32x2;

__device__ inline unsigned short f2bf(float x) {
    unsigned u = __float_as_uint(x);
    u += 0x7FFF + ((u >> 16) & 1);          // round-to-nearest-even
    return (unsigned short)(u >> 16);
}
__device__ inline float bf2f(unsigned short b) {
    return __uint_as_float(((unsigned)b) << 16);
}
__device__ inline __half2 u2h2(unsigned u) {
    return __builtin_bit_cast(__half2, u);
}

__device__ inline bf16x8 pack8(float4 a, float4 b) {
    bf16x8 r;
    r[0] = (short)f2bf(a.x); r[1] = (short)f2bf(a.y);
    r[2] = (short)f2bf(a.z); r[3] = (short)f2bf(a.w);
    r[4] = (short)f2bf(b.x); r[5] = (short)f2bf(b.y);
    r[6] = (short)f2bf(b.z); r[7] = (short)f2bf(b.w);
    return r;
}

// Dual-source projection: out[m][n] = f16/bf16( sum_d X[m][d]*W[n][d] ),
// d<64, n<NT*16. Blocks [0,nb1) -> X1/out1, rest -> X2/out2. MFMA, no LDS.
template<int NT, bool F16>
__global__ void proj_mfma2_kernel(const float* __restrict__ X1, int n1,
                                  const float* __restrict__ X2, int n2,
                                  const float* __restrict__ W,
                                  unsigned short* __restrict__ out1,
                                  unsigned short* __restrict__ out2) {
    int nb1 = (n1 + 63) / 64;
    const float* X; unsigned short* out; int nrows, mblk;
    if ((int)blockIdx.x < nb1) { X = X1; out = out1; nrows = n1; mblk = blockIdx.x; }
    else                        { X = X2; out = out2; nrows = n2; mblk = blockIdx.x - nb1; }

    int lane = threadIdx.x & 63;
    int wv   = threadIdx.x >> 6;
    int m0   = (mblk * 4 + wv) * 16;
    if (m0 >= nrows) return;
    int lr = lane & 15;        // row-in-tile for A/B, col for C
    int lk = lane >> 4;        // k-block 0..3 for A/B, row-block for C

    bf16x8 bfr[NT][2];
#pragma unroll
    for (int nt = 0; nt < NT; ++nt)
#pragma unroll
        for (int ks = 0; ks < 2; ++ks) {
            const float* wp = W + (size_t)(nt * 16 + lr) * 64 + ks * 32 + lk * 8;
            float4 w0 = *(const float4*)wp;
            float4 w1 = *(const float4*)(wp + 4);
            bfr[nt][ks] = pack8(w0, w1);
        }

    int row = m0 + lr;
    if (row >= nrows) row = nrows - 1;
    const float* xp = X + (size_t)row * 64 + lk * 8;
    float4 x0 = *(const float4*)xp;
    float4 x1 = *(const float4*)(xp + 4);
    float4 x2 = *(const float4*)(xp + 32);
    float4 x3 = *(const float4*)(xp + 36);
    bf16x8 a0 = pack8(x0, x1);
    bf16x8 a1 = pack8(x2, x3);

    f32x4 acc[NT];
#pragma unroll
    for (int nt = 0; nt < NT; ++nt) {
        acc[nt] = (f32x4){0.f, 0.f, 0.f, 0.f};
        acc[nt] = __builtin_amdgcn_mfma_f32_16x16x32_bf16(a0, bfr[nt][0], acc[nt], 0, 0, 0);
        acc[nt] = __builtin_amdgcn_mfma_f32_16x16x32_bf16(a1, bfr[nt][1], acc[nt], 0, 0, 0);
    }

#pragma unroll
    for (int nt = 0; nt < NT; ++nt)
#pragma unroll
        for (int r = 0; r < 4; ++r) {
            int ro = m0 + lk * 4 + r;
            if (ro < nrows) {
                unsigned short bits;
                if (F16) {
                    __half h = __float2half(acc[nt][r]);
                    bits = __builtin_bit_cast(unsigned short, h);
                } else {
                    bits = f2bf(acc[nt][r]);
                }
                out[(size_t)ro * (NT * 16) + nt * 16 + lr] = bits;
            }
        }
}

__global__ void qproj_bf16_kernel(const int* __restrict__ q_rel, const float* __restrict__ rela,
                                  const float* __restrict__ Wqr, const float* __restrict__ bqr,
                                  unsigned* __restrict__ Qb, int batch) {
    int tid = threadIdx.x;
    int b = tid >> 5, k = tid & 31;
    if (b >= batch) return;
    int qr = q_rel[b];
    const float* x = rela + (size_t)qr * 64;
    const float* w = Wqr + (size_t)k * 64;
    float acc = bqr[k];
    for (int d = 0; d < 64; ++d) acc += w[d] * x[d];
    float other = __shfl_xor(acc, 1, 64);
    if ((k & 1) == 0) {
        unsigned lo = f2bf(acc), hi = f2bf(other);
        Qb[b * 16 + (k >> 1)] = lo | (hi << 16);
    }
}

// ---- sort stage 1: pack records + coarse histogram (obj>>8, 512 bins) ----
// 256 threads * 32 edges = 8192 edges/block.
// pk2[e] = { sub | rel<<17 | ridx<<26 , obj }
__global__ void pack_hist_kernel(const int4* __restrict__ edges4, int2* __restrict__ pk2,
                                 int* __restrict__ hmat, int n_edge, int NB) {
    __shared__ int hist[512];
    int tid = threadIdx.x, blk = blockIdx.x;
    hist[tid] = 0;
    hist[tid + 256] = 0;
    __syncthreads();
    int unit0 = blk * 2048;   // 4-edge units per block: 8192/4 = 2048
#pragma unroll
    for (int k = 0; k < 8; ++k) {
        int u = unit0 + k * 256 + tid;
        int base = u * 4;
        if (base >= n_edge) break;
        if (base + 4 <= n_edge) {
            const int4* p = edges4 + (size_t)u * 6;
            int4 v0 = p[0], v1 = p[1], v2 = p[2], v3 = p[3], v4 = p[4], v5 = p[5];
            atomicAdd(&hist[v1.y >> 8], 1);
            atomicAdd(&hist[v2.w >> 8], 1);
            atomicAdd(&hist[v4.y >> 8], 1);
            atomicAdd(&hist[v5.w >> 8], 1);
            int4 o0, o1;
            o0.x = v1.x | (v0.z << 17) | (v0.x << 26); o0.y = v1.y;
            o0.z = v2.z | (v2.x << 17) | (v1.z << 26); o0.w = v2.w;
            o1.x = v4.x | (v3.z << 17) | (v3.x << 26); o1.y = v4.y;
            o1.z = v5.z | (v5.x << 17) | (v4.z << 26); o1.w = v5.w;
            int4* q = (int4*)pk2 + (size_t)u * 2;
            q[0] = o0;
            q[1] = o1;
        } else {
            const int* ei = (const int*)edges4;
            for (int e = base; e < n_edge; ++e) {
                const int* ep = ei + (size_t)e * 6;
                int ridx = ep[0], rel = ep[2], sub = ep[4], obj = ep[5];
                atomicAdd(&hist[obj >> 8], 1);
                pk2[e] = make_int2(sub | (rel << 17) | (ridx << 26), obj);
            }
        }
    }
    __syncthreads();
    hmat[tid * NB + blk] = hist[tid];               // bin-major for the scan
    hmat[(tid + 256) * NB + blk] = hist[tid + 256];
}

// ---- multi-block exclusive scan (in[0..N) -> out[0..N], out[N]=total) ----
#define SCAN_CHUNK 1024

__global__ void scan_partial_kernel(const int* __restrict__ counts, int* __restrict__ bsum,
                                    int N) {
    __shared__ int s[256];
    int base = blockIdx.x * SCAN_CHUNK;
    int tid = threadIdx.x;
    int sum = 0;
#pragma unroll
    for (int k = 0; k < 4; ++k) {
        int idx = base + k * 256 + tid;
        if (idx < N) sum += counts[idx];
    }
    s[tid] = sum;
    __syncthreads();
    for (int off = 128; off > 0; off >>= 1) {
        if (tid < off) s[tid] += s[tid + off];
        __syncthreads();
    }
    if (tid == 0) bsum[blockIdx.x] = s[0];
}

__global__ void scan_bsum_kernel(int* __restrict__ bsum, int* __restrict__ offs, int B, int N) {
    __shared__ int s[1024];
    int tid = threadIdx.x;
    int v = (tid < B) ? bsum[tid] : 0;
    s[tid] = v;
    __syncthreads();
    for (int off = 1; off < 1024; off <<= 1) {
        int t = (tid >= off) ? s[tid - off] : 0;
        __syncthreads();
        s[tid] += t;
        __syncthreads();
    }
    if (tid < B) bsum[tid] = s[tid] - v;   // exclusive block prefix
    if (tid == 0) offs[N] = s[1023];       // grand total
}

__global__ void scan_final_kernel(const int* __restrict__ counts, const int* __restrict__ bsum,
                                  int* __restrict__ offs, int N) {
    __shared__ int s[256];
    int base = blockIdx.x * SCAN_CHUNK;
    int tid = threadIdx.x;
    int v[4];
    int sum = 0;
#pragma unroll
    for (int k = 0; k < 4; ++k) {
        int idx = base + tid * 4 + k;
        v[k] = (idx < N) ? counts[idx] : 0;
        sum += v[k];
    }
    s[tid] = sum;
    __syncthreads();
    for (int off = 1; off < 256; off <<= 1) {
        int t = (tid >= off) ? s[tid - off] : 0;
        __syncthreads();
        s[tid] += t;
        __syncthreads();
    }
    int run = bsum[blockIdx.x] + s[tid] - sum;
#pragma unroll
    for (int k = 0; k < 4; ++k) {
        int idx = base + tid * 4 + k;
        if (idx < N) offs[idx] = run;
        run += v[k];
    }
}

// ---- sort stage 2: LDS-staged scatter into coarse buckets ----
// 512 threads, 8192 records/block held in registers (16/thread); local 512-bin
// counting sort in LDS; burst writes: consecutive lanes -> consecutive global
// addresses within each bucket run (vs 64-way scattered 8B stores).
__global__ __launch_bounds__(512) void scatter1_kernel(const int2* __restrict__ pk2,
                                                       const int* __restrict__ hscan,
                                                       int2* __restrict__ outrec,
                                                       int n_edge, int NB) {
    __shared__ int lhist[512];
    __shared__ int lincl[512];   // inclusive prefix
    __shared__ int lcur[512];    // placement cursor (starts at exclusive base)
    __shared__ int gbase[512];   // global base of this block's run per bucket
    __shared__ int2 st[8192];    // 64 KB bucket-sorted stage
    int tid = threadIdx.x, blk = blockIdx.x;
    int start_e = blk * 8192;
    int cnt = n_edge - start_e;
    if (cnt > 8192) cnt = 8192;
    lhist[tid] = 0;
    gbase[tid] = hscan[tid * NB + blk];
    __syncthreads();
    int2 r[16];
#pragma unroll
    for (int k = 0; k < 16; ++k) {
        int idx = tid + k * 512;
        if (idx < cnt) {
            r[k] = pk2[start_e + idx];
            atomicAdd(&lhist[(r[k].y >> 8) & 511], 1);
        }
    }
    __syncthreads();
    int h = lhist[tid];
    lincl[tid] = h;
    __syncthreads();
    for (int off = 1; off < 512; off <<= 1) {
        int t = (tid >= off) ? lincl[tid - off] : 0;
        __syncthreads();
        lincl[tid] += t;
        __syncthreads();
    }
    lcur[tid] = lincl[tid] - h;          // exclusive base
    __syncthreads();
#pragma unroll
    for (int k = 0; k < 16; ++k) {
        int idx = tid + k * 512;
        if (idx < cnt) {
            int b = (r[k].y >> 8) & 511;
            int p = atomicAdd(&lcur[b], 1);
            st[p] = r[k];
        }
    }
    __syncthreads();
    for (int i = tid; i < cnt; i += 512) {
        int2 rec = st[i];
        int b = (rec.y >> 8) & 511;
        int lrank = i - (lincl[b] - lhist[b]);
        outrec[gbase[b] + lrank] = rec;   // consecutive i -> consecutive addr
    }
}

// ---- sort stage 3: per-bucket LDS counting sort by obj&255 ----
// 512 blocks (one per coarse bucket), 67KB LDS -> 2 blocks/CU resident.
// Emits SORTED 4B HEADERS into hdrS and offs[obj] = bucket_start + within-
// bucket exclusive base (covers obj == n_node too).
#define BS_CAP 8192
__global__ __launch_bounds__(512) void bucket_sort_kernel(const int2* __restrict__ in,
                                                          const int* __restrict__ hscan,
                                                          int* __restrict__ hdrS,
                                                          int* __restrict__ offs,
                                                          int NB, int n_node) {
    __shared__ int hist[256];
    __shared__ int sbase[256];
    __shared__ int cur[256];
    __shared__ int2 st[BS_CAP];          // 64 KB stage
    int b = blockIdx.x, tid = threadIdx.x;
    int start = hscan[b * NB];
    int end   = hscan[(b + 1) * NB];
    int size  = end - start;
    if (tid < 256) hist[tid] = 0;
    __syncthreads();
    bool inlds = (size <= BS_CAP);
    if (inlds) {
        for (int i = tid; i < size; i += 512) {
            int2 v = in[start + i];
            st[i] = v;
            atomicAdd(&hist[v.y & 255], 1);
        }
    } else {
        for (int i = tid; i < size; i += 512) {
            int2 v = in[start + i];
            atomicAdd(&hist[v.y & 255], 1);
        }
    }
    __syncthreads();
    int h = 0;
    if (tid < 256) { h = hist[tid]; sbase[tid] = h; }
    __syncthreads();
    for (int off = 1; off < 256; off <<= 1) {
        int t = (tid >= off && tid < 256) ? sbase[tid - off] : 0;
        __syncthreads();
        if (tid < 256) sbase[tid] += t;
        __syncthreads();
    }
    if (tid < 256) {
        int ebase = sbase[tid] - h;      // exclusive base within bucket
        cur[tid] = ebase;
        int obj = (b << 8) | tid;
        if (obj <= n_node) offs[obj] = start + ebase;
    }
    __syncthreads();
    if (inlds) {
        for (int i = tid; i < size; i += 512) {
            int2 r = st[i];
            int p = atomicAdd(&cur[r.y & 255], 1);
            hdrS[start + p] = r.x;
        }
    } else {
        for (int i = tid; i < size; i += 512) {
            int2 r = in[start + i];
            int p = atomicAdd(&cur[r.y & 255], 1);
            hdrS[start + p] = r.x;
        }
    }
}

__device__ inline float edot(unsigned sv, unsigned rv, unsigned qv, float2 w) {
    float a0 = fmaxf(bf2f((unsigned short)sv) + bf2f((unsigned short)rv)
                     + bf2f((unsigned short)qv), 0.f);
    float a1 = fmaxf(bf2f((unsigned short)(sv >> 16)) + bf2f((unsigned short)(rv >> 16))
                     + bf2f((unsigned short)(qv >> 16)), 0.f);
    return a0 * w.x + a1 * w.y;
}

// 16 lanes per group, 4 SORTED headers per group (one int4 broadcast load);
// writes the 4B alpha array contiguously.
__global__ void alpha_kernel(const int* __restrict__ hdrS,
                             const unsigned* __restrict__ Sb,
                             const unsigned* __restrict__ Rb,
                             const unsigned* __restrict__ Qb,
                             const float2* __restrict__ w2,
                             const float* __restrict__ w_alpha_b,
                             float* __restrict__ af,
                             int n_edge) {
    int tid = threadIdx.x;
    int lane = tid & 15;
    int e0 = (blockIdx.x * 16 + (tid >> 4)) * 4;
    if (e0 >= n_edge) return;
    int4 h4 = *(const int4*)(hdrS + e0);   // may overread <=12B into workspace (safe)
    int h0 = h4.x, h1 = h4.y, h2 = h4.z, h3 = h4.w;
    float2 w = w2[lane];
    unsigned sv0 = Sb[(size_t)(h0 & 0x1FFFF) * 16 + lane];
    unsigned sv1 = Sb[(size_t)(h1 & 0x1FFFF) * 16 + lane];
    unsigned sv2 = Sb[(size_t)(h2 & 0x1FFFF) * 16 + lane];
    unsigned sv3 = Sb[(size_t)(h3 & 0x1FFFF) * 16 + lane];
    unsigned rv0 = Rb[(size_t)((h0 >> 17) & 0x1FF) * 16 + lane];
    unsigned rv1 = Rb[(size_t)((h1 >> 17) & 0x1FF) * 16 + lane];
    unsigned rv2 = Rb[(size_t)((h2 >> 17) & 0x1FF) * 16 + lane];
    unsigned rv3 = Rb[(size_t)((h3 >> 17) & 0x1FF) * 16 + lane];
    unsigned qv0 = Qb[((h0 >> 26) & 7) * 16 + lane];
    unsigned qv1 = Qb[((h1 >> 26) & 7) * 16 + lane];
    unsigned qv2 = Qb[((h2 >> 26) & 7) * 16 + lane];
    unsigned qv3 = Qb[((h3 >> 26) & 7) * 16 + lane];
    float p0 = edot(sv0, rv0, qv0, w);
    float p1 = edot(sv1, rv1, qv1, w);
    float p2 = edot(sv2, rv2, qv2, w);
    float p3 = edot(sv3, rv3, qv3, w);
#pragma unroll
    for (int off = 8; off > 0; off >>= 1) {
        p0 += __shfl_xor(p0, off, 16);
        p1 += __shfl_xor(p1, off, 16);
        p2 += __shfl_xor(p2, off, 16);
        p3 += __shfl_xor(p3, off, 16);
    }
    if (lane < 4 && e0 + lane < n_edge) {
        float p = p0;
        if (lane == 1) p = p1;
        if (lane == 2) p = p2;
        if (lane == 3) p = p3;
        float alpha = 1.f / (1.f + __expf(-(p + w_alpha_b[0])));
        af[e0 + lane] = alpha;                // contiguous (sorted order)
    }
}

// reduce (R19 form, split streams): one 64-lane wave per node; coalesced
// {hdr, alpha} batch preload; depth-4 software-pipelined gathers of the f16
// Wh tables (slot broadcast via bpermute); packed-f16 accumulate.
__global__ void reduce_kernel(const int* __restrict__ hdrS, const float* __restrict__ af,
                              const int* __restrict__ offs,
                              const uint2* __restrict__ Hw2,
                              const uint2* __restrict__ Rw2,
                              float4* __restrict__ out4, int n_node) {
    int lane = threadIdx.x & 63;
    int node = blockIdx.x * 4 + (threadIdx.x >> 6);
    if (node >= n_node) return;
    int g = lane >> 4;        // record subgroup 0..3
    int t = lane & 15;        // dim-quad index 0..15
    int start = offs[node], end = offs[node + 1];
    __half2 acc0 = __float2half2_rn(0.f);
    __half2 acc1 = __float2half2_rn(0.f);

    for (int i = start; i < end; i += 64) {
        int m = end - i;
        if (m > 64) m = 64;
        float a = 0.f;        // a=0 for idle lanes -> tail records contribute 0
        int pk = 0;
        if (lane < m) {
            a  = __builtin_nontemporal_load(&af[i + lane]);
            pk = __builtin_nontemporal_load(&hdrS[i + lane]);
        }
        int nj = (m + 3) >> 2;

        __half2 A0, A1, A2, A3;
        uint2 H0, H1, H2, H3, R0, R1, R2, R3;

#define RD_ISSUE(S, J) do {                                                   \
        int src_ = 4 * (J) + g;                                               \
        bool ok_ = (src_ < m);                                                \
        int s_ = ok_ ? src_ : 0;                                              \
        float a_ = __shfl(a, s_, 64);                                         \
        int p_ = __shfl(pk, s_, 64);                                          \
        A##S = __float2half2_rn(ok_ ? a_ : 0.f);                              \
        int sub_ = p_ & 0x1FFFF, rel_ = (p_ >> 17) & 0x1FF;                   \
        H##S = Hw2[(size_t)sub_ * 16 + t];                                    \
        R##S = Rw2[(size_t)rel_ * 16 + t];                                    \
    } while (0)

#define RD_CONSUME(S) do {                                                    \
        acc0 = __hfma2(A##S, __hadd2(u2h2(H##S.x), u2h2(R##S.x)), acc0);      \
        acc1 = __hfma2(A##S, __hadd2(u2h2(H##S.y), u2h2(R##S.y)), acc1);      \
    } while (0)

        RD_ISSUE(0, 0);
        RD_ISSUE(1, 1);
        RD_ISSUE(2, 2);
        RD_ISSUE(3, 3);
        for (int j = 0; j < nj; j += 4) {
            RD_CONSUME(0); RD_ISSUE(0, j + 4);
            RD_CONSUME(1); RD_ISSUE(1, j + 5);
            RD_CONSUME(2); RD_ISSUE(2, j + 6);
            RD_CONSUME(3); RD_ISSUE(3, j + 7);
        }
#undef RD_ISSUE
#undef RD_CONSUME
    }
    float2 f0 = __half22float2(acc0);
    float2 f1 = __half22float2(acc1);
    f32x4 acc = (f32x4){f0.x, f0.y, f1.x, f1.y};
#pragma unroll
    for (int off = 16; off <= 32; off <<= 1) {
        acc.x += __shfl_xor(acc.x, off, 64);
        acc.y += __shfl_xor(acc.y, off, 64);
        acc.z += __shfl_xor(acc.z, off, 64);
        acc.w += __shfl_xor(acc.w, off, 64);
    }
    if (g == 0)
        __builtin_nontemporal_store(acc, (f32x4*)&out4[(size_t)node * 16 + t]);
}

extern "C" void kernel_launch(void* const* d_in, const int* in_sizes, int n_in,
                              void* d_out, int out_size, void* d_ws, size_t ws_size,
                              hipStream_t stream) {
    const int*   q_rel     = (const int*)d_in[1];
    const float* hidden    = (const float*)d_in[2];
    const int*   edges     = (const int*)d_in[3];
    const float* rela      = (const float*)d_in[7];
    const float* Ws        = (const float*)d_in[8];
    const float* Wr        = (const float*)d_in[9];
    const float* Wqr       = (const float*)d_in[10];
    const float* bqr       = (const float*)d_in[11];
    const float* w_alpha_w = (const float*)d_in[12];
    const float* w_alpha_b = (const float*)d_in[13];
    const float* Wh        = (const float*)d_in[14];

    int n_node = in_sizes[2] / 64;
    int n_edge = in_sizes[3] / 6;
    int n_rel  = in_sizes[7] / 64;
    int batch  = in_sizes[1];

    int NB = (n_edge + 8191) / 8192;        // pack/scatter blocks (8192 edges each)
    int N2 = NB * 512;                      // hmat length (512 coarse buckets)
    int n_sblk2 = (N2 + SCAN_CHUNK - 1) / SCAN_CHUNK;

    // workspace layout (~41 MB):
    //   regionP (16 MB): pack_hist out; after scatter1 reused as hdrS (8) + af (8)
    //   regionQ (16 MB): scatter1 out; after bucket_sort reused as Hw/Rw
    unsigned* Sb   = (unsigned*)d_ws;                     // n_node*16 uints (6.4 MB)
    unsigned* Rb   = Sb + (size_t)n_node * 16;            // n_rel*16
    unsigned* Qb   = Rb + (size_t)n_rel * 16;             // batch*16
    int*   offs    = (int*)(Qb + (size_t)batch * 16);     // n_node+1
    int*   bsum    = offs + n_node + 1;                   // 1024
    int*   hmat    = bsum + 1024;                         // N2
    int*   hscan   = hmat + N2;                           // N2+1
    size_t rec_off = (size_t)(hscan + N2 + 1 - (int*)d_ws);
    rec_off = (rec_off + 3) & ~(size_t)3;                 // align 16B
    int2*  regP    = (int2*)((int*)d_ws + rec_off);       // n_edge int2 (16 MB)
    int2*  regQ    = regP + n_edge;                       // n_edge int2 (16 MB)
    int*   hdrS    = (int*)regP;                          // sorted headers (8 MB)
    float* af      = (float*)(hdrS + n_edge);             // alpha array (8 MB)
    unsigned short* Hw = (unsigned short*)regQ;           // n_node*64 f16 (12.8 MB)
    unsigned short* Rw = Hw + (size_t)n_node * 64;        // n_rel*64 - fits in regQ

    {
        int nb = (n_node + 63) / 64 + (n_rel + 63) / 64;
        proj_mfma2_kernel<2, false><<<nb, 256, 0, stream>>>(
            hidden, n_node, rela, n_rel, Ws, (unsigned short*)Sb, (unsigned short*)Rb);
    }
    qproj_bf16_kernel<<<1, 256, 0, stream>>>(q_rel, rela, Wqr, bqr, Qb, batch);

    // --- counting sort by obj (no global atomics) ---
    pack_hist_kernel<<<NB, 256, 0, stream>>>((const int4*)edges, regP, hmat, n_edge, NB);

    scan_partial_kernel<<<n_sblk2, 256, 0, stream>>>(hmat, bsum, N2);
    scan_bsum_kernel<<<1, 1024, 0, stream>>>(bsum, hscan, n_sblk2, N2);
    scan_final_kernel<<<n_sblk2, 256, 0, stream>>>(hmat, bsum, hscan, N2);

    scatter1_kernel<<<NB, 512, 0, stream>>>(regP, hscan, regQ, n_edge, NB);
    bucket_sort_kernel<<<512, 512, 0, stream>>>(regQ, hscan, hdrS, offs, NB, n_node);

    alpha_kernel<<<(n_edge + 63) / 64, 256, 0, stream>>>(
        hdrS, Sb, Rb, Qb, (const float2*)w_alpha_w, w_alpha_b, af, n_edge);

    // build Wh-projected f16 gather tables AFTER bucket_sort (overlay regQ)
    {
        int nb = (n_node + 63) / 64 + (n_rel + 63) / 64;
        proj_mfma2_kernel<4, true><<<nb, 256, 0, stream>>>(
            hidden, n_node, rela, n_rel, Wh, Hw, Rw);
    }

    reduce_kernel<<<(n_node + 3) / 4, 256, 0, stream>>>(
        hdrS, af, offs, (const uint2*)Hw, (const uint2*)Rw, (float4*)d_out, n_node);
}